// Round 14
// baseline (71.512 us; speedup 1.0000x reference)
//
#include <hip/hip_runtime.h>
#include <hip/hip_bf16.h>

#define BATCH 4
#define TOK   2304
#define CH    512
#define NHEAD 8
#define HDIM  64
#define F3    1536
#define YB_STRIDE ((long)TOK * F3)   // y per-batch stride (elements)
#define QKV_SZ    ((long)TOK * CH)   // one Q/K/V third (elements)
#define KVCHUNK   9                  // token chunks for K^T V partials (2304/9=256)

typedef __attribute__((ext_vector_type(8))) short short8;   // 8 bf16 = 4 VGPRs
typedef __attribute__((ext_vector_type(4))) float f32x4;

__device__ inline ushort f2b(float f) {
    __hip_bfloat16 h = __float2bfloat16(f);
    return *reinterpret_cast<ushort*>(&h);
}
__device__ inline void unp(unsigned int u, float& lo, float& hi) {
    union { unsigned int i; float f; } a, c;
    a.i = u << 16; c.i = u & 0xffff0000u;
    lo = a.f; hi = c.f;
}

// global -> LDS direct copy, 16B per lane; lds dest = wave-uniform base + lane*16
#define GLL(gp, lp) __builtin_amdgcn_global_load_lds( \
    (const __attribute__((address_space(1))) unsigned int*)(gp), \
    (__attribute__((address_space(3))) unsigned int*)(lp), 16, 0, 0)

// ---------------------------------------------------------------------------
// K0: fp32 -> bf16 convert for x and w_in in one launch (wb contiguous after xb)
// ---------------------------------------------------------------------------
__global__ __launch_bounds__(256) void cvt_bf16_2(
    const float* __restrict__ x, const float* __restrict__ w,
    ushort* __restrict__ xb_wb, int nx4, int nw4)
{
    const int i = blockIdx.x * 256 + threadIdx.x;
    float4 v;
    if (i < nx4)                v = ((const float4*)x)[i];
    else if (i < nx4 + nw4)     v = ((const float4*)w)[i - nx4];
    else return;
    ushort4 o;
    o.x = f2b(v.x); o.y = f2b(v.y); o.z = f2b(v.z); o.w = f2b(v.w);
    ((ushort4*)xb_wb)[i] = o;
}

// ---------------------------------------------------------------------------
// K1: 256x256-tile, BK=64, 8-wave (2Mx4N), 8-phase counted-vmcnt MFMA GEMM NT.
// (verified r5-r12) READ-SEAL: P1:Bhi(t+1)[other buf] P3:Alo(t+2) P4:Ahi,Blo(t+2)
// Ledger: end-of-t VMC(6) leaves {Alo,Ahi,Blo}(t+2) in flight; t=NT-2: VMC(0).
// ---------------------------------------------------------------------------
template<int KDIM, bool OUT_BF16>
__global__ __launch_bounds__(512, 2) void gemm256_8ph(
    const ushort* __restrict__ A, const ushort* __restrict__ B,
    const float* __restrict__ bias, void* __restrict__ Cout, int N)
{
    constexpr int NT = KDIM / 64;
    __shared__ __align__(16) char smem[131072];

    const int tid  = threadIdx.x;
    const int lane = tid & 63, wave = tid >> 6;
    const int wm = wave >> 2, wn = wave & 3;           // 2 x 4 wave grid

    // T1 XCD swizzle (nwg % 8 == 0 by construction: 216 blocks)
    const int nbx  = gridDim.x;
    const int flat = blockIdx.x + nbx * blockIdx.y;
    const int cpx  = (nbx * gridDim.y) >> 3;
    const int swz  = (flat & 7) * cpx + (flat >> 3);
    const int row0 = (swz / nbx) * 256, col0 = (swz % nbx) * 256;

    // staging invariants: thread covers LDS linear (srow, (tid&7)*16B) per chunk
    const int srow = tid >> 3;                          // 0..63 within chunk
    const int scol = ((tid & 7) ^ (srow & 7)) << 3;     // inverse-swizzled src col (elems)
    const ushort* gA = A + (long)(row0 + srow) * KDIM + scol;
    const ushort* gB = B + (long)(col0 + srow) * KDIM + scol;
    char* ldsW = smem + wave * 1024;                    // + op*65536 + buf*32768 + half*16384 + chunk*8192

    // fragment-read invariants
    const int l15 = lane & 15, lg = lane >> 4, l7 = lane & 7;
    const int cp[2] = { (lg * 16) ^ (l7 * 16), (64 + lg * 16) ^ (l7 * 16) };
    const char* rdA = smem + (wm * 128 + l15) * 128;
    const char* rdB = smem + 65536 + (wn * 64 + l15) * 128;

    f32x4  acc[8][4] = {};
    short8 a[2][4][2], b[2][2];

#define STAGE8(op, t, h) do { \
    const ushort* _g = ((op) ? gB : gA) + ((h) * 128) * KDIM + (t) * 64; \
    char* _l = ldsW + (op) * 65536 + ((t) & 1) * 32768 + (h) * 16384; \
    GLL(_g, _l); \
    GLL(_g + 64 * KDIM, _l + 8192); \
} while (0)

#define LDA8(t, mh) do { \
    const char* _p = rdA + ((t) & 1) * 32768 + (mh) * 8192; \
    _Pragma("unroll") for (int mf = 0; mf < 4; ++mf) { \
        a[mh][mf][0] = *(const short8*)(_p + mf * 2048 + cp[0]); \
        a[mh][mf][1] = *(const short8*)(_p + mf * 2048 + cp[1]); } \
} while (0)

#define LDB8(t, nh) do { \
    const char* _p = rdB + ((t) & 1) * 32768 + (nh) * 4096; \
    _Pragma("unroll") for (int j = 0; j < 2; ++j) { \
        b[j][0] = *(const short8*)(_p + j * 2048 + cp[0]); \
        b[j][1] = *(const short8*)(_p + j * 2048 + cp[1]); } \
} while (0)

#define MFMAQ(mh, nh) do { \
    _Pragma("unroll") for (int mf = 0; mf < 4; ++mf) \
    _Pragma("unroll") for (int j = 0; j < 2; ++j) \
    _Pragma("unroll") for (int ks = 0; ks < 2; ++ks) \
        acc[(mh)*4+mf][(nh)*2+j] = __builtin_amdgcn_mfma_f32_16x16x32_bf16( \
            a[mh][mf][ks], b[j][ks], acc[(mh)*4+mf][(nh)*2+j], 0, 0, 0); \
} while (0)

#define BAR8() __builtin_amdgcn_s_barrier()
#define VMC(n) asm volatile("s_waitcnt vmcnt(" #n ")" ::: "memory")

    // ---- prologue: tile0 (4 half-tiles) + tile1 {Blo, Alo, Ahi}
    STAGE8(0, 0, 0); STAGE8(0, 0, 1); STAGE8(1, 0, 0); STAGE8(1, 0, 1);
    VMC(4);
    STAGE8(1, 1, 0); STAGE8(0, 1, 0); STAGE8(0, 1, 1);
    VMC(6);                               // 14 issued, retire oldest 8 = all tile0
    BAR8();

#pragma unroll
    for (int t = 0; t < NT; ++t) {
        // P1: quadrant (0,0)
        LDA8(t, 0); LDB8(t, 0);
        if (t + 1 < NT) STAGE8(1, t + 1, 1);          // Bhi(t+1) -> other buf (always safe)
        BAR8(); __builtin_amdgcn_s_setprio(1); MFMAQ(0, 0); __builtin_amdgcn_s_setprio(0); BAR8();
        // P2: quadrant (1,0) — no staging (no region is sealed yet)
        LDA8(t, 1);
        BAR8(); __builtin_amdgcn_s_setprio(1); MFMAQ(1, 0); __builtin_amdgcn_s_setprio(0); BAR8();
        // P3: quadrant (0,1); A reads sealed by P2-end barrier
        LDB8(t, 1);
        if (t + 2 < NT) STAGE8(0, t + 2, 0);          // Alo(t+2)
        BAR8(); __builtin_amdgcn_s_setprio(1); MFMAQ(0, 1); __builtin_amdgcn_s_setprio(0); BAR8();
        // P4: quadrant (1,1); B reads sealed by P3-end barrier
        if (t + 2 < NT) { STAGE8(0, t + 2, 1);        // Ahi(t+2)
                          STAGE8(1, t + 2, 0); }      // Blo(t+2)
        BAR8(); __builtin_amdgcn_s_setprio(1); MFMAQ(1, 1); __builtin_amdgcn_s_setprio(0);
        if (t + 2 < NT)      { VMC(6); }              // retire Bhi(t+1): tile t+1 landed
        else if (t + 1 < NT) { VMC(0); }              // drain before last tile
        if (t + 1 < NT) BAR8();
    }

    // ---- epilogue: D row=(lane>>4)*4+reg, col=lane&15 (m89-verified)
    const int rb = row0 + wm * 128 + lg * 4;
    const int cb = col0 + wn * 64 + l15;
#pragma unroll
    for (int mf = 0; mf < 8; ++mf) {
#pragma unroll
        for (int nf = 0; nf < 4; ++nf) {
            const int c = cb + nf * 16;
            const float bv = bias[c];
            const long base = (long)(rb + mf * 16) * N + c;
#pragma unroll
            for (int r = 0; r < 4; ++r) {
                const float v = acc[mf][nf][r] + bv;
                if (OUT_BF16) ((ushort*)Cout)[base + (long)r * N] = f2b(v);
                else          ((float*)Cout)[base + (long)r * N]  = v;
            }
        }
    }
#undef STAGE8
#undef LDA8
#undef LDB8
#undef MFMAQ
#undef BAR8
#undef VMC
}

// ---------------------------------------------------------------------------
// K3 GEMM (REVERTED to r8-verified BK=32 m97 structure + T1 XCD swizzle).
// ---------------------------------------------------------------------------
template<bool OUT_BF16>
__global__ __launch_bounds__(256) void mfma_gemm_nt(
    const ushort* __restrict__ A, const ushort* __restrict__ B,
    const float* __restrict__ bias, void* __restrict__ Cout,
    int M, int N, int K, long sA, long sB, long sC)
{
    // T1 XCD swizzle over the flattened 3D grid
    const int gx = gridDim.x, gxy = gridDim.x * gridDim.y;
    const int flat = blockIdx.x + gx * blockIdx.y + gxy * blockIdx.z;
    const int cpx  = (gxy * gridDim.z) >> 3;
    const int swz  = (flat & 7) * cpx + (flat >> 3);
    const int bz = swz / gxy, rem = swz % gxy;
    const int row0 = (rem / gx) * 128, col0 = (rem % gx) * 128;

    A += (long)bz * sA;
    B += (long)bz * sB;

    __shared__ __align__(16) ushort As[128 * 32];
    __shared__ __align__(16) ushort Bs[128 * 32];

    const int tid  = threadIdx.x;
    const int lane = tid & 63;
    const int wave = tid >> 6;
    const int wr   = (wave >> 1) * 64;
    const int wc   = (wave & 1) * 64;

    const int sr = tid >> 2;
    const int sc = (tid & 3) * 8;
    const ushort* gA0 = A + (long)(row0 + sr) * K + sc;
    const ushort* gA1 = A + (long)(row0 + sr + 64) * K + sc;
    const ushort* gB0 = B + (long)(col0 + sr) * K + sc;
    const ushort* gB1 = B + (long)(col0 + sr + 64) * K + sc;

    char* lA = (char*)As + wave * 1024;
    char* lB = (char*)Bs + wave * 1024;

    const int fr = lane & 15;
    const int kg = (lane >> 4) * 8;

    f32x4 acc[4][4] = {};

    for (int k0 = 0; k0 < K; k0 += 32) {
        if (k0) __syncthreads();
        GLL(gA0 + k0, lA);
        GLL(gA1 + k0, lA + 4096);
        GLL(gB0 + k0, lB);
        GLL(gB1 + k0, lB + 4096);
        __syncthreads();

        short8 a[4], b[4];
        #pragma unroll
        for (int m = 0; m < 4; ++m)
            a[m] = *(const short8*)(As + (wr + m * 16 + fr) * 32 + kg);
        #pragma unroll
        for (int n = 0; n < 4; ++n)
            b[n] = *(const short8*)(Bs + (wc + n * 16 + fr) * 32 + kg);

        #pragma unroll
        for (int m = 0; m < 4; ++m)
            #pragma unroll
            for (int n = 0; n < 4; ++n)
                acc[m][n] = __builtin_amdgcn_mfma_f32_16x16x32_bf16(
                    a[m], b[n], acc[m][n], 0, 0, 0);
    }

    const int rbase = row0 + wr + (lane >> 4) * 4;
    const int cbase = col0 + wc + (lane & 15);
    const long zoff = (long)bz * sC;
    #pragma unroll
    for (int m = 0; m < 4; ++m) {
        #pragma unroll
        for (int n = 0; n < 4; ++n) {
            const int c = cbase + n * 16;
            const float bv = bias[c];
            #pragma unroll
            for (int r = 0; r < 4; ++r) {
                const long off = zoff + (long)(rbase + m * 16 + r) * N + c;
                const float v = acc[m][n][r] + bv;
                if (OUT_BF16) ((ushort*)Cout)[off] = f2b(v);
                else          ((float*)Cout)[off]  = v;
            }
        }
    }
}

// ---------------------------------------------------------------------------
// K2a (r10-verified): partial sums over a 256-token chunk, stored TRANSPOSED
// (V-dim first), bf16: Mtp[chunk][bh][dp][d] = bf16((1/8) Σ V[n][dp] K[n][d])
// ---------------------------------------------------------------------------
__global__ __launch_bounds__(256) void ktv_partial(
    const ushort* __restrict__ y, ushort* __restrict__ Mtp)
{
    const int chunk = blockIdx.x;          // 0..8 (256 tokens each)
    const int bh    = blockIdx.y;          // 0..31
    const int b = bh >> 3, h = bh & 7;
    const ushort* Kp = y + (long)b * YB_STRIDE + QKV_SZ     + h * HDIM;
    const ushort* Vp = y + (long)b * YB_STRIDE + 2 * QKV_SZ + h * HDIM;

    __shared__ __align__(16) float Ks[64][68];
    __shared__ __align__(16) float Vs[64][68];

    const int tid = threadIdx.x;
    const int tx = tid & 15, ty = tid >> 4;
    const int lr = tid >> 2;
    const int ls = (tid & 3) * 16;

    float acc[4][4] = {};                  // [i -> d (K-dim)][j -> dp (V-dim)]

    for (int s = 0; s < 4; ++s) {
        const int n0 = chunk * 256 + s * 64;
        const ushort* kr = Kp + (long)(n0 + lr) * CH + ls;
        const ushort* vr = Vp + (long)(n0 + lr) * CH + ls;
        const uint4 k0 = *(const uint4*)kr;
        const uint4 k1 = *(const uint4*)(kr + 8);
        const uint4 v0 = *(const uint4*)vr;
        const uint4 v1 = *(const uint4*)(vr + 8);
        if (s) __syncthreads();
        unsigned int kw[8] = {k0.x,k0.y,k0.z,k0.w,k1.x,k1.y,k1.z,k1.w};
        unsigned int vw[8] = {v0.x,v0.y,v0.z,v0.w,v1.x,v1.y,v1.z,v1.w};
        #pragma unroll
        for (int u = 0; u < 4; ++u) {      // packed: 8 x ds_write_b128
            float4 kf, vf;
            unp(kw[2*u],   kf.x, kf.y); unp(kw[2*u+1], kf.z, kf.w);
            unp(vw[2*u],   vf.x, vf.y); unp(vw[2*u+1], vf.z, vf.w);
            *(float4*)&Ks[lr][ls + 4*u] = kf;
            *(float4*)&Vs[lr][ls + 4*u] = vf;
        }
        __syncthreads();

        #pragma unroll 8
        for (int nn = 0; nn < 64; ++nn) {
            const float4 ka = *(const float4*)&Ks[nn][ty * 4];
            const float4 vb = *(const float4*)&Vs[nn][tx * 4];
            const float kk[4] = {ka.x, ka.y, ka.z, ka.w};
            const float vv[4] = {vb.x, vb.y, vb.z, vb.w};
            #pragma unroll
            for (int i = 0; i < 4; ++i)
                #pragma unroll
                for (int j = 0; j < 4; ++j)
                    acc[i][j] = fmaf(kk[i], vv[j], acc[i][j]);
        }
        __syncthreads();
    }

    // TRANSPOSED store (V-dim first), bf16: Mo[dp][d], dp = tx*4+j, d = ty*4+i
    ushort* Mo = Mtp + ((long)chunk * 32 + bh) * 4096;
    #pragma unroll
    for (int j = 0; j < 4; ++j) {
        ushort4 st;
        st.x = f2b(acc[0][j] * 0.125f); st.y = f2b(acc[1][j] * 0.125f);
        st.z = f2b(acc[2][j] * 0.125f); st.w = f2b(acc[3][j] * 0.125f);
        *(ushort4*)&Mo[(tx * 4 + j) * 64 + ty * 4] = st;
    }
}

// ---------------------------------------------------------------------------
// K2b (r13 REWRITE — access pattern only, same math/geometry):
//   Pt[b][f][64h+q] = sum_e w_out[f][64h+e] * Ms[e][q]
// Fixes the 66us pig found in r12 rocprof (latency-bound scalar loads):
//  (1) chunk reduction: thread owns 16 CONTIGUOUS elems -> 2 x uint4 per chunk
//      (18 vector loads vs 144 scalar 2B loads)
//  (2) w_out slice staged to LDS Ws[64][68] via float4 (kills 256 scalar
//      global loads in compute loop; reads become wave-broadcast LDS hits)
// ---------------------------------------------------------------------------
__global__ __launch_bounds__(256) void fold_pt(
    const ushort* __restrict__ Mtp, const float* __restrict__ w_out,
    ushort* __restrict__ Pt)
{
    const int fc = blockIdx.x;   // 0..7
    const int bh = blockIdx.y;   // 0..31
    const int b = bh >> 3, h = bh & 7;

    __shared__ __align__(16) float Ms[64][68];   // [dp(V-dim)][q(K-dim)]
    __shared__ __align__(16) float Ws[64][68];   // [f-local][e(V-dim)]

    const int tid = threadIdx.x;
    const int tx = tid & 15, ty = tid >> 4;
    const int r  = tid >> 2, c0 = (tid & 3) * 16;   // 16-elem slot: e0 = r*64+c0

    // stage Ws[i][d] = w_out[(fc*64+i)*CH + h*64 + d]  (float4 coalesced)
    {
        const float* wr_ = w_out + (long)(fc * 64 + r) * CH + h * HDIM + c0;
        #pragma unroll
        for (int k = 0; k < 4; ++k)
            *(float4*)&Ws[r][c0 + 4 * k] = *(const float4*)(wr_ + 4 * k);
    }

    // stage Ms[dp][q] = sum_c Mtp[c][bh][e0..e0+16)  (vectorized reduction)
    {
        const int e0 = tid * 16;
        float s[16] = {};
        #pragma unroll
        for (int c = 0; c < KVCHUNK; ++c) {
            const ushort* p = Mtp + ((long)c * 32 + bh) * 4096 + e0;
            const uint4 u0 = *(const uint4*)p;
            const uint4 u1 = *(const uint4*)(p + 8);
            const unsigned int uu[8] = {u0.x,u0.y,u0.z,u0.w,u1.x,u1.y,u1.z,u1.w};
            #pragma unroll
            for (int k = 0; k < 8; ++k) {
                float lo, hi; unp(uu[k], lo, hi);
                s[2*k] += lo; s[2*k+1] += hi;
            }
        }
        #pragma unroll
        for (int k = 0; k < 4; ++k) {
            float4 v; v.x = s[4*k]; v.y = s[4*k+1]; v.z = s[4*k+2]; v.w = s[4*k+3];
            *(float4*)&Ms[r][c0 + 4 * k] = v;   // e0 = r*64 + c0 -> Ms[r][c0..]
        }
    }
    __syncthreads();

    float acc[4][4] = {};
    for (int d = 0; d < 64; ++d) {               // d = V-dim contraction
        const float4 mv = *(const float4*)&Ms[d][tx * 4];
        const float mm[4] = {mv.x, mv.y, mv.z, mv.w};
        #pragma unroll
        for (int i = 0; i < 4; ++i) {
            const float w = Ws[ty * 4 + i][d];   // broadcast across tx lanes
            #pragma unroll
            for (int j = 0; j < 4; ++j)
                acc[i][j] = fmaf(w, mm[j], acc[i][j]);
        }
    }
    const int fbase = fc * 64 + ty * 4;
    #pragma unroll
    for (int i = 0; i < 4; ++i) {
        ushort4 o;
        o.x = f2b(acc[i][0]); o.y = f2b(acc[i][1]);
        o.z = f2b(acc[i][2]); o.w = f2b(acc[i][3]);
        *(ushort4*)&Pt[(((long)b * CH) + fbase + i) * CH + h * HDIM + tx * 4] = o;
    }
}

// ---------------------------------------------------------------------------
extern "C" void kernel_launch(void* const* d_in, const int* in_sizes, int n_in,
                              void* d_out, int out_size, void* d_ws, size_t ws_size,
                              hipStream_t stream)
{
    const float* x     = (const float*)d_in[0];   // [4,2304,512]
    const float* w_in  = (const float*)d_in[1];   // [1536,512]
    const float* b_in  = (const float*)d_in[2];   // [1536]
    const float* w_out = (const float*)d_in[3];   // [512,512]
    const float* b_out = (const float*)d_in[4];   // [512]
    float* out = (float*)d_out;                   // [4,2304,512] fp32

    char* ws = (char*)d_ws;
    ushort* xb   = (ushort*)ws;                      //  9,437,184 B
    ushort* wb   = (ushort*)(ws + 9437184);          //  1,572,864 B (contig after xb)
    ushort* y    = (ushort*)(ws + 11010048);         // 28,311,552 B bf16 [4][2304][1536]
    ushort* Mtp  = (ushort*)(ws + 39321600);         //  2,359,296 B (9 chunks, bf16)
    ushort* Pt   = (ushort*)(ws + 41680896);         //  2,097,152 B -> 43.8 MB total

    // K0: converts (one launch; wb contiguous after xb)
    cvt_bf16_2<<<5376, 256, 0, stream>>>(x, w_in, xb, 1179648, 196608);

    // K1: y = x @ w_in^T + b_in  (bf16 out), 256^2 8-phase. M=9216 N=1536 K=512
    gemm256_8ph<512, true><<<dim3(F3 / 256, (BATCH * TOK) / 256), 512, 0, stream>>>(
        xb, wb, b_in, y, F3);

    // K2a: chunk-partial (V^T K)/8, bf16 out
    ktv_partial<<<dim3(KVCHUNK, BATCH * NHEAD), 256, 0, stream>>>(y, Mtp);

    // K2b: vectorized reduce + fold w_out -> Pt bf16
    fold_pt<<<dim3(8, BATCH * NHEAD), 256, 0, stream>>>(Mtp, w_out, Pt);

    // K3: out[b] = Q[b] @ Pt[b]^T + b_out (fp32 out), M=2304 N=512 K=512, z=4
    mfma_gemm_nt<false><<<dim3(CH / 128, TOK / 128, BATCH), 256, 0, stream>>>(
        y, Pt, b_out, out, TOK, CH, CH, YB_STRIDE, (long)CH * CH, QKV_SZ);
}

// Round 15
// 60.171 us; speedup vs baseline: 1.1885x; 1.1885x over previous
//
#include <hip/hip_runtime.h>
#include <hip/hip_bf16.h>

#define BATCH 4
#define TOK   2304
#define CH    512
#define NHEAD 8
#define HDIM  64
#define F3    1536
#define YB_STRIDE ((long)TOK * F3)   // y per-batch stride (elements)
#define QKV_SZ    ((long)TOK * CH)   // one Q/K/V third (elements)
#define KVCHUNK   6                  // token chunks for K^T V partials (2304/6=384)

typedef __attribute__((ext_vector_type(8))) short short8;   // 8 bf16 = 4 VGPRs
typedef __attribute__((ext_vector_type(4))) float f32x4;

__device__ inline ushort f2b(float f) {
    __hip_bfloat16 h = __float2bfloat16(f);
    return *reinterpret_cast<ushort*>(&h);
}
__device__ inline void unp(unsigned int u, float& lo, float& hi) {
    union { unsigned int i; float f; } a, c;
    a.i = u << 16; c.i = u & 0xffff0000u;
    lo = a.f; hi = c.f;
}

// global -> LDS direct copy, 16B per lane; lds dest = wave-uniform base + lane*16
#define GLL(gp, lp) __builtin_amdgcn_global_load_lds( \
    (const __attribute__((address_space(1))) unsigned int*)(gp), \
    (__attribute__((address_space(3))) unsigned int*)(lp), 16, 0, 0)

// ---------------------------------------------------------------------------
// K0: fp32 -> bf16 convert for x and w_in in one launch (wb contiguous after xb)
// ---------------------------------------------------------------------------
__global__ __launch_bounds__(256) void cvt_bf16_2(
    const float* __restrict__ x, const float* __restrict__ w,
    ushort* __restrict__ xb_wb, int nx4, int nw4)
{
    const int i = blockIdx.x * 256 + threadIdx.x;
    float4 v;
    if (i < nx4)                v = ((const float4*)x)[i];
    else if (i < nx4 + nw4)     v = ((const float4*)w)[i - nx4];
    else return;
    ushort4 o;
    o.x = f2b(v.x); o.y = f2b(v.y); o.z = f2b(v.z); o.w = f2b(v.w);
    ((ushort4*)xb_wb)[i] = o;
}

// ---------------------------------------------------------------------------
// K1: 256x256-tile, BK=64, 8-wave (2Mx4N), 8-phase counted-vmcnt MFMA GEMM NT.
// (verified r5-r14) READ-SEAL: P1:Bhi(t+1)[other buf] P3:Alo(t+2) P4:Ahi,Blo(t+2)
// Ledger: end-of-t VMC(6) leaves {Alo,Ahi,Blo}(t+2) in flight; t=NT-2: VMC(0).
// ---------------------------------------------------------------------------
template<int KDIM, bool OUT_BF16>
__global__ __launch_bounds__(512, 2) void gemm256_8ph(
    const ushort* __restrict__ A, const ushort* __restrict__ B,
    const float* __restrict__ bias, void* __restrict__ Cout, int N)
{
    constexpr int NT = KDIM / 64;
    __shared__ __align__(16) char smem[131072];

    const int tid  = threadIdx.x;
    const int lane = tid & 63, wave = tid >> 6;
    const int wm = wave >> 2, wn = wave & 3;           // 2 x 4 wave grid

    // T1 XCD swizzle (nwg % 8 == 0 by construction: 216 blocks)
    const int nbx  = gridDim.x;
    const int flat = blockIdx.x + nbx * blockIdx.y;
    const int cpx  = (nbx * gridDim.y) >> 3;
    const int swz  = (flat & 7) * cpx + (flat >> 3);
    const int row0 = (swz / nbx) * 256, col0 = (swz % nbx) * 256;

    // staging invariants: thread covers LDS linear (srow, (tid&7)*16B) per chunk
    const int srow = tid >> 3;                          // 0..63 within chunk
    const int scol = ((tid & 7) ^ (srow & 7)) << 3;     // inverse-swizzled src col (elems)
    const ushort* gA = A + (long)(row0 + srow) * KDIM + scol;
    const ushort* gB = B + (long)(col0 + srow) * KDIM + scol;
    char* ldsW = smem + wave * 1024;                    // + op*65536 + buf*32768 + half*16384 + chunk*8192

    // fragment-read invariants
    const int l15 = lane & 15, lg = lane >> 4, l7 = lane & 7;
    const int cp[2] = { (lg * 16) ^ (l7 * 16), (64 + lg * 16) ^ (l7 * 16) };
    const char* rdA = smem + (wm * 128 + l15) * 128;
    const char* rdB = smem + 65536 + (wn * 64 + l15) * 128;

    f32x4  acc[8][4] = {};
    short8 a[2][4][2], b[2][2];

#define STAGE8(op, t, h) do { \
    const ushort* _g = ((op) ? gB : gA) + ((h) * 128) * KDIM + (t) * 64; \
    char* _l = ldsW + (op) * 65536 + ((t) & 1) * 32768 + (h) * 16384; \
    GLL(_g, _l); \
    GLL(_g + 64 * KDIM, _l + 8192); \
} while (0)

#define LDA8(t, mh) do { \
    const char* _p = rdA + ((t) & 1) * 32768 + (mh) * 8192; \
    _Pragma("unroll") for (int mf = 0; mf < 4; ++mf) { \
        a[mh][mf][0] = *(const short8*)(_p + mf * 2048 + cp[0]); \
        a[mh][mf][1] = *(const short8*)(_p + mf * 2048 + cp[1]); } \
} while (0)

#define LDB8(t, nh) do { \
    const char* _p = rdB + ((t) & 1) * 32768 + (nh) * 4096; \
    _Pragma("unroll") for (int j = 0; j < 2; ++j) { \
        b[j][0] = *(const short8*)(_p + j * 2048 + cp[0]); \
        b[j][1] = *(const short8*)(_p + j * 2048 + cp[1]); } \
} while (0)

#define MFMAQ(mh, nh) do { \
    _Pragma("unroll") for (int mf = 0; mf < 4; ++mf) \
    _Pragma("unroll") for (int j = 0; j < 2; ++j) \
    _Pragma("unroll") for (int ks = 0; ks < 2; ++ks) \
        acc[(mh)*4+mf][(nh)*2+j] = __builtin_amdgcn_mfma_f32_16x16x32_bf16( \
            a[mh][mf][ks], b[j][ks], acc[(mh)*4+mf][(nh)*2+j], 0, 0, 0); \
} while (0)

#define BAR8() __builtin_amdgcn_s_barrier()
#define VMC(n) asm volatile("s_waitcnt vmcnt(" #n ")" ::: "memory")

    // ---- prologue: tile0 (4 half-tiles) + tile1 {Blo, Alo, Ahi}
    STAGE8(0, 0, 0); STAGE8(0, 0, 1); STAGE8(1, 0, 0); STAGE8(1, 0, 1);
    VMC(4);
    STAGE8(1, 1, 0); STAGE8(0, 1, 0); STAGE8(0, 1, 1);
    VMC(6);                               // 14 issued, retire oldest 8 = all tile0
    BAR8();

#pragma unroll
    for (int t = 0; t < NT; ++t) {
        // P1: quadrant (0,0)
        LDA8(t, 0); LDB8(t, 0);
        if (t + 1 < NT) STAGE8(1, t + 1, 1);          // Bhi(t+1) -> other buf (always safe)
        BAR8(); __builtin_amdgcn_s_setprio(1); MFMAQ(0, 0); __builtin_amdgcn_s_setprio(0); BAR8();
        // P2: quadrant (1,0) — no staging (no region is sealed yet)
        LDA8(t, 1);
        BAR8(); __builtin_amdgcn_s_setprio(1); MFMAQ(1, 0); __builtin_amdgcn_s_setprio(0); BAR8();
        // P3: quadrant (0,1); A reads sealed by P2-end barrier
        LDB8(t, 1);
        if (t + 2 < NT) STAGE8(0, t + 2, 0);          // Alo(t+2)
        BAR8(); __builtin_amdgcn_s_setprio(1); MFMAQ(0, 1); __builtin_amdgcn_s_setprio(0); BAR8();
        // P4: quadrant (1,1); B reads sealed by P3-end barrier
        if (t + 2 < NT) { STAGE8(0, t + 2, 1);        // Ahi(t+2)
                          STAGE8(1, t + 2, 0); }      // Blo(t+2)
        BAR8(); __builtin_amdgcn_s_setprio(1); MFMAQ(1, 1); __builtin_amdgcn_s_setprio(0);
        if (t + 2 < NT)      { VMC(6); }              // retire Bhi(t+1): tile t+1 landed
        else if (t + 1 < NT) { VMC(0); }              // drain before last tile
        if (t + 1 < NT) BAR8();
    }

    // ---- epilogue: D row=(lane>>4)*4+reg, col=lane&15 (m89-verified)
    const int rb = row0 + wm * 128 + lg * 4;
    const int cb = col0 + wn * 64 + l15;
#pragma unroll
    for (int mf = 0; mf < 8; ++mf) {
#pragma unroll
        for (int nf = 0; nf < 4; ++nf) {
            const int c = cb + nf * 16;
            const float bv = bias[c];
            const long base = (long)(rb + mf * 16) * N + c;
#pragma unroll
            for (int r = 0; r < 4; ++r) {
                const float v = acc[mf][nf][r] + bv;
                if (OUT_BF16) ((ushort*)Cout)[base + (long)r * N] = f2b(v);
                else          ((float*)Cout)[base + (long)r * N]  = v;
            }
        }
    }
#undef STAGE8
#undef LDA8
#undef LDB8
#undef MFMAQ
#undef BAR8
#undef VMC
}

// ---------------------------------------------------------------------------
// K3 GEMM (r8-verified BK=32 m97 structure + T1 XCD swizzle).
// ---------------------------------------------------------------------------
template<bool OUT_BF16>
__global__ __launch_bounds__(256) void mfma_gemm_nt(
    const ushort* __restrict__ A, const ushort* __restrict__ B,
    const float* __restrict__ bias, void* __restrict__ Cout,
    int M, int N, int K, long sA, long sB, long sC)
{
    // T1 XCD swizzle over the flattened 3D grid
    const int gx = gridDim.x, gxy = gridDim.x * gridDim.y;
    const int flat = blockIdx.x + gx * blockIdx.y + gxy * blockIdx.z;
    const int cpx  = (gxy * gridDim.z) >> 3;
    const int swz  = (flat & 7) * cpx + (flat >> 3);
    const int bz = swz / gxy, rem = swz % gxy;
    const int row0 = (rem / gx) * 128, col0 = (rem % gx) * 128;

    A += (long)bz * sA;
    B += (long)bz * sB;

    __shared__ __align__(16) ushort As[128 * 32];
    __shared__ __align__(16) ushort Bs[128 * 32];

    const int tid  = threadIdx.x;
    const int lane = tid & 63;
    const int wave = tid >> 6;
    const int wr   = (wave >> 1) * 64;
    const int wc   = (wave & 1) * 64;

    const int sr = tid >> 2;
    const int sc = (tid & 3) * 8;
    const ushort* gA0 = A + (long)(row0 + sr) * K + sc;
    const ushort* gA1 = A + (long)(row0 + sr + 64) * K + sc;
    const ushort* gB0 = B + (long)(col0 + sr) * K + sc;
    const ushort* gB1 = B + (long)(col0 + sr + 64) * K + sc;

    char* lA = (char*)As + wave * 1024;
    char* lB = (char*)Bs + wave * 1024;

    const int fr = lane & 15;
    const int kg = (lane >> 4) * 8;

    f32x4 acc[4][4] = {};

    for (int k0 = 0; k0 < K; k0 += 32) {
        if (k0) __syncthreads();
        GLL(gA0 + k0, lA);
        GLL(gA1 + k0, lA + 4096);
        GLL(gB0 + k0, lB);
        GLL(gB1 + k0, lB + 4096);
        __syncthreads();

        short8 a[4], b[4];
        #pragma unroll
        for (int m = 0; m < 4; ++m)
            a[m] = *(const short8*)(As + (wr + m * 16 + fr) * 32 + kg);
        #pragma unroll
        for (int n = 0; n < 4; ++n)
            b[n] = *(const short8*)(Bs + (wc + n * 16 + fr) * 32 + kg);

        #pragma unroll
        for (int m = 0; m < 4; ++m)
            #pragma unroll
            for (int n = 0; n < 4; ++n)
                acc[m][n] = __builtin_amdgcn_mfma_f32_16x16x32_bf16(
                    a[m], b[n], acc[m][n], 0, 0, 0);
    }

    const int rbase = row0 + wr + (lane >> 4) * 4;
    const int cbase = col0 + wc + (lane & 15);
    const long zoff = (long)bz * sC;
    #pragma unroll
    for (int m = 0; m < 4; ++m) {
        #pragma unroll
        for (int n = 0; n < 4; ++n) {
            const int c = cbase + n * 16;
            const float bv = bias[c];
            #pragma unroll
            for (int r = 0; r < 4; ++r) {
                const long off = zoff + (long)(rbase + m * 16 + r) * N + c;
                const float v = acc[m][n][r] + bv;
                if (OUT_BF16) ((ushort*)Cout)[off] = f2b(v);
                else          ((float*)Cout)[off]  = v;
            }
        }
    }
}

// ---------------------------------------------------------------------------
// K2a (r15 MFMA rewrite, proven primitives only — no tr_read):
//   Mtp[chunk][bh][e][q] = bf16( (1/8) * sum_{n in chunk} V[n][e] * K[n][q] )
// Stage K,V sub-tiles TRANSPOSED [d][tok] in LDS via scalar ds_write_u16 with
// K1's XOR swizzle (ushort idx: col ^ ((row&7)<<3)). Fragments read with
// IDENTICAL addressing for A(K-tile) and B(V-tile) -> k-slot map cancels
// (same argument as all passing NT GEMMs). C/D = m89 map. 4 waves split e.
// ---------------------------------------------------------------------------
__global__ __launch_bounds__(256) void ktv_mfma(
    const ushort* __restrict__ y, ushort* __restrict__ Mtp)
{
    const int chunk = blockIdx.x;          // 0..5 (384 tokens each)
    const int bh    = blockIdx.y;          // 0..31
    const int b = bh >> 3, h = bh & 7;
    const ushort* Kp = y + (long)b * YB_STRIDE + QKV_SZ     + h * HDIM;
    const ushort* Vp = y + (long)b * YB_STRIDE + 2 * QKV_SZ + h * HDIM;

    __shared__ __align__(16) ushort Kt[64 * 64];   // [d][tok], swizzled, 8 KB
    __shared__ __align__(16) ushort Vt[64 * 64];

    const int tid  = threadIdx.x;
    const int lane = tid & 63, w = tid >> 6;       // wave w owns e-block 16w
    const int tloc = tid >> 2;                     // staged token 0..63
    const int d0   = (tid & 3) * 16;               // staged d range

    const int fr = lane & 15;                      // fragment row (q or e)
    const int kg = (lane >> 4) * 8;                // token chunk within k-step
    const int swr = (fr & 7) << 3;                 // read-side XOR (ushort units)

    f32x4 acc[4] = {};                             // m=0..3 -> q-blocks 16m

    for (int s = 0; s < 6; ++s) {
        const int n0 = chunk * 384 + s * 64;
        // load 16 d-contiguous bf16 of K and V for token (n0+tloc)
        const ushort* kr = Kp + (long)(n0 + tloc) * CH + d0;
        const ushort* vr = Vp + (long)(n0 + tloc) * CH + d0;
        const uint4 k0 = *(const uint4*)kr;
        const uint4 k1 = *(const uint4*)(kr + 8);
        const uint4 v0 = *(const uint4*)vr;
        const uint4 v1 = *(const uint4*)(vr + 8);
        if (s) __syncthreads();                    // prev reads done before overwrite
        const unsigned int kw[8] = {k0.x,k0.y,k0.z,k0.w,k1.x,k1.y,k1.z,k1.w};
        const unsigned int vw[8] = {v0.x,v0.y,v0.z,v0.w,v1.x,v1.y,v1.z,v1.w};
        #pragma unroll
        for (int j = 0; j < 16; ++j) {             // transpose-scatter to [d][tok]
            const int d   = d0 + j;
            const int idx = d * 64 + (tloc ^ ((d & 7) << 3));
            const ushort kv = (ushort)(kw[j >> 1] >> ((j & 1) * 16));
            const ushort vv = (ushort)(vw[j >> 1] >> ((j & 1) * 16));
            Kt[idx] = kv;
            Vt[idx] = vv;
        }
        __syncthreads();

        short8 a[4][2], bfrag[2];
        #pragma unroll
        for (int ks = 0; ks < 2; ++ks) {
            const int kc = (kg + 32 * ks) ^ swr;   // swizzled token col (mult of 8)
            bfrag[ks] = *(const short8*)(Vt + (16 * w + fr) * 64 + kc);
            #pragma unroll
            for (int m = 0; m < 4; ++m)
                a[m][ks] = *(const short8*)(Kt + (16 * m + fr) * 64 + kc);
        }
        #pragma unroll
        for (int ks = 0; ks < 2; ++ks)
            #pragma unroll
            for (int m = 0; m < 4; ++m)
                acc[m] = __builtin_amdgcn_mfma_f32_16x16x32_bf16(
                    a[m][ks], bfrag[ks], acc[m], 0, 0, 0);
    }

    // D: q = 16m + (lane>>4)*4 + r, e = 16w + fr (m89). Store Mo[e][q] (V-major).
    ushort* Mo = Mtp + ((long)chunk * 32 + bh) * 4096;
    const int e  = 16 * w + fr;
    const int lg = lane >> 4;
    #pragma unroll
    for (int m = 0; m < 4; ++m) {
        ushort4 st;
        st.x = f2b(acc[m][0] * 0.125f); st.y = f2b(acc[m][1] * 0.125f);
        st.z = f2b(acc[m][2] * 0.125f); st.w = f2b(acc[m][3] * 0.125f);
        *(ushort4*)&Mo[e * 64 + 16 * m + lg * 4] = st;
    }
}

// ---------------------------------------------------------------------------
// K2b (r14-verified vectorized): Pt[b][f][64h+q] = sum_e w_out[f][64h+e]*Ms[e][q]
// ---------------------------------------------------------------------------
__global__ __launch_bounds__(256) void fold_pt(
    const ushort* __restrict__ Mtp, const float* __restrict__ w_out,
    ushort* __restrict__ Pt)
{
    const int fc = blockIdx.x;   // 0..7
    const int bh = blockIdx.y;   // 0..31
    const int b = bh >> 3, h = bh & 7;

    __shared__ __align__(16) float Ms[64][68];   // [e(V-dim)][q(K-dim)]
    __shared__ __align__(16) float Ws[64][68];   // [f-local][e(V-dim)]

    const int tid = threadIdx.x;
    const int tx = tid & 15, ty = tid >> 4;
    const int r  = tid >> 2, c0 = (tid & 3) * 16;

    {
        const float* wr_ = w_out + (long)(fc * 64 + r) * CH + h * HDIM + c0;
        #pragma unroll
        for (int k = 0; k < 4; ++k)
            *(float4*)&Ws[r][c0 + 4 * k] = *(const float4*)(wr_ + 4 * k);
    }

    {
        const int e0 = tid * 16;
        float s[16] = {};
        #pragma unroll
        for (int c = 0; c < KVCHUNK; ++c) {
            const ushort* p = Mtp + ((long)c * 32 + bh) * 4096 + e0;
            const uint4 u0 = *(const uint4*)p;
            const uint4 u1 = *(const uint4*)(p + 8);
            const unsigned int uu[8] = {u0.x,u0.y,u0.z,u0.w,u1.x,u1.y,u1.z,u1.w};
            #pragma unroll
            for (int k = 0; k < 8; ++k) {
                float lo, hi; unp(uu[k], lo, hi);
                s[2*k] += lo; s[2*k+1] += hi;
            }
        }
        #pragma unroll
        for (int k = 0; k < 4; ++k) {
            float4 v; v.x = s[4*k]; v.y = s[4*k+1]; v.z = s[4*k+2]; v.w = s[4*k+3];
            *(float4*)&Ms[r][c0 + 4 * k] = v;
        }
    }
    __syncthreads();

    float acc[4][4] = {};
    for (int d = 0; d < 64; ++d) {
        const float4 mv = *(const float4*)&Ms[d][tx * 4];
        const float mm[4] = {mv.x, mv.y, mv.z, mv.w};
        #pragma unroll
        for (int i = 0; i < 4; ++i) {
            const float w = Ws[ty * 4 + i][d];
            #pragma unroll
            for (int j = 0; j < 4; ++j)
                acc[i][j] = fmaf(w, mm[j], acc[i][j]);
        }
    }
    const int fbase = fc * 64 + ty * 4;
    #pragma unroll
    for (int i = 0; i < 4; ++i) {
        ushort4 o;
        o.x = f2b(acc[i][0]); o.y = f2b(acc[i][1]);
        o.z = f2b(acc[i][2]); o.w = f2b(acc[i][3]);
        *(ushort4*)&Pt[(((long)b * CH) + fbase + i) * CH + h * HDIM + tx * 4] = o;
    }
}

// ---------------------------------------------------------------------------
extern "C" void kernel_launch(void* const* d_in, const int* in_sizes, int n_in,
                              void* d_out, int out_size, void* d_ws, size_t ws_size,
                              hipStream_t stream)
{
    const float* x     = (const float*)d_in[0];   // [4,2304,512]
    const float* w_in  = (const float*)d_in[1];   // [1536,512]
    const float* b_in  = (const float*)d_in[2];   // [1536]
    const float* w_out = (const float*)d_in[3];   // [512,512]
    const float* b_out = (const float*)d_in[4];   // [512]
    float* out = (float*)d_out;                   // [4,2304,512] fp32

    char* ws = (char*)d_ws;
    ushort* xb   = (ushort*)ws;                      //  9,437,184 B
    ushort* wb   = (ushort*)(ws + 9437184);          //  1,572,864 B (contig after xb)
    ushort* y    = (ushort*)(ws + 11010048);         // 28,311,552 B bf16 [4][2304][1536]
    ushort* Mtp  = (ushort*)(ws + 39321600);         //  1,572,864 B (6 chunks, bf16)
    ushort* Pt   = (ushort*)(ws + 40894464);         //  2,097,152 B -> 43.0 MB total

    // K0: converts (one launch; wb contiguous after xb)
    cvt_bf16_2<<<5376, 256, 0, stream>>>(x, w_in, xb, 1179648, 196608);

    // K1: y = x @ w_in^T + b_in  (bf16 out), 256^2 8-phase. M=9216 N=1536 K=512
    gemm256_8ph<512, true><<<dim3(F3 / 256, (BATCH * TOK) / 256), 512, 0, stream>>>(
        xb, wb, b_in, y, F3);

    // K2a: chunk-partial (V^T K)/8 via MFMA, 192 blocks (1 round)
    ktv_mfma<<<dim3(KVCHUNK, BATCH * NHEAD), 256, 0, stream>>>(y, Mtp);

    // K2b: vectorized reduce + fold w_out -> Pt bf16
    fold_pt<<<dim3(8, BATCH * NHEAD), 256, 0, stream>>>(Mtp, w_out, Pt);

    // K3: out[b] = Q[b] @ Pt[b]^T + b_out (fp32 out), M=2304 N=512 K=512, z=4
    mfma_gemm_nt<false><<<dim3(CH / 128, TOK / 128, BATCH), 256, 0, stream>>>(
        y, Pt, b_out, out, TOK, CH, CH, YB_STRIDE, (long)CH * CH, QKV_SZ);
}

// Round 16
// 57.966 us; speedup vs baseline: 1.2337x; 1.0381x over previous
//
#include <hip/hip_runtime.h>
#include <hip/hip_bf16.h>

#define BATCH 4
#define TOK   2304
#define CH    512
#define NHEAD 8
#define HDIM  64
#define F3    1536
#define YB_STRIDE ((long)TOK * F3)   // y per-batch stride (elements)
#define QKV_SZ    ((long)TOK * CH)   // one Q/K/V third (elements)
#define KVCHUNK   6                  // token chunks for K^T V partials (2304/6=384)

typedef __attribute__((ext_vector_type(8))) short short8;   // 8 bf16 = 4 VGPRs
typedef __attribute__((ext_vector_type(4))) float f32x4;

__device__ inline ushort f2b(float f) {
    __hip_bfloat16 h = __float2bfloat16(f);
    return *reinterpret_cast<ushort*>(&h);
}
__device__ inline void unp(unsigned int u, float& lo, float& hi) {
    union { unsigned int i; float f; } a, c;
    a.i = u << 16; c.i = u & 0xffff0000u;
    lo = a.f; hi = c.f;
}

// global -> LDS direct copy, 16B per lane; lds dest = wave-uniform base + lane*16
#define GLL(gp, lp) __builtin_amdgcn_global_load_lds( \
    (const __attribute__((address_space(1))) unsigned int*)(gp), \
    (__attribute__((address_space(3))) unsigned int*)(lp), 16, 0, 0)

// ---------------------------------------------------------------------------
// K0: fp32 -> bf16 convert for x and w_in in one launch (wb contiguous after xb)
// ---------------------------------------------------------------------------
__global__ __launch_bounds__(256) void cvt_bf16_2(
    const float* __restrict__ x, const float* __restrict__ w,
    ushort* __restrict__ xb_wb, int nx4, int nw4)
{
    const int i = blockIdx.x * 256 + threadIdx.x;
    float4 v;
    if (i < nx4)                v = ((const float4*)x)[i];
    else if (i < nx4 + nw4)     v = ((const float4*)w)[i - nx4];
    else return;
    ushort4 o;
    o.x = f2b(v.x); o.y = f2b(v.y); o.z = f2b(v.z); o.w = f2b(v.w);
    ((ushort4*)xb_wb)[i] = o;
}

// ---------------------------------------------------------------------------
// K1: 256x256-tile, BK=64, 8-wave (2Mx4N), 8-phase counted-vmcnt MFMA GEMM NT.
// (verified r5-r15) READ-SEAL: P1:Bhi(t+1)[other buf] P3:Alo(t+2) P4:Ahi,Blo(t+2)
// Ledger: end-of-t VMC(6) leaves {Alo,Ahi,Blo}(t+2) in flight; t=NT-2: VMC(0).
// ---------------------------------------------------------------------------
template<int KDIM, bool OUT_BF16>
__global__ __launch_bounds__(512, 2) void gemm256_8ph(
    const ushort* __restrict__ A, const ushort* __restrict__ B,
    const float* __restrict__ bias, void* __restrict__ Cout, int N)
{
    constexpr int NT = KDIM / 64;
    __shared__ __align__(16) char smem[131072];

    const int tid  = threadIdx.x;
    const int lane = tid & 63, wave = tid >> 6;
    const int wm = wave >> 2, wn = wave & 3;           // 2 x 4 wave grid

    // T1 XCD swizzle (nwg % 8 == 0 by construction: 216 blocks)
    const int nbx  = gridDim.x;
    const int flat = blockIdx.x + nbx * blockIdx.y;
    const int cpx  = (nbx * gridDim.y) >> 3;
    const int swz  = (flat & 7) * cpx + (flat >> 3);
    const int row0 = (swz / nbx) * 256, col0 = (swz % nbx) * 256;

    // staging invariants: thread covers LDS linear (srow, (tid&7)*16B) per chunk
    const int srow = tid >> 3;                          // 0..63 within chunk
    const int scol = ((tid & 7) ^ (srow & 7)) << 3;     // inverse-swizzled src col (elems)
    const ushort* gA = A + (long)(row0 + srow) * KDIM + scol;
    const ushort* gB = B + (long)(col0 + srow) * KDIM + scol;
    char* ldsW = smem + wave * 1024;                    // + op*65536 + buf*32768 + half*16384 + chunk*8192

    // fragment-read invariants
    const int l15 = lane & 15, lg = lane >> 4, l7 = lane & 7;
    const int cp[2] = { (lg * 16) ^ (l7 * 16), (64 + lg * 16) ^ (l7 * 16) };
    const char* rdA = smem + (wm * 128 + l15) * 128;
    const char* rdB = smem + 65536 + (wn * 64 + l15) * 128;

    f32x4  acc[8][4] = {};
    short8 a[2][4][2], b[2][2];

#define STAGE8(op, t, h) do { \
    const ushort* _g = ((op) ? gB : gA) + ((h) * 128) * KDIM + (t) * 64; \
    char* _l = ldsW + (op) * 65536 + ((t) & 1) * 32768 + (h) * 16384; \
    GLL(_g, _l); \
    GLL(_g + 64 * KDIM, _l + 8192); \
} while (0)

#define LDA8(t, mh) do { \
    const char* _p = rdA + ((t) & 1) * 32768 + (mh) * 8192; \
    _Pragma("unroll") for (int mf = 0; mf < 4; ++mf) { \
        a[mh][mf][0] = *(const short8*)(_p + mf * 2048 + cp[0]); \
        a[mh][mf][1] = *(const short8*)(_p + mf * 2048 + cp[1]); } \
} while (0)

#define LDB8(t, nh) do { \
    const char* _p = rdB + ((t) & 1) * 32768 + (nh) * 4096; \
    _Pragma("unroll") for (int j = 0; j < 2; ++j) { \
        b[j][0] = *(const short8*)(_p + j * 2048 + cp[0]); \
        b[j][1] = *(const short8*)(_p + j * 2048 + cp[1]); } \
} while (0)

#define MFMAQ(mh, nh) do { \
    _Pragma("unroll") for (int mf = 0; mf < 4; ++mf) \
    _Pragma("unroll") for (int j = 0; j < 2; ++j) \
    _Pragma("unroll") for (int ks = 0; ks < 2; ++ks) \
        acc[(mh)*4+mf][(nh)*2+j] = __builtin_amdgcn_mfma_f32_16x16x32_bf16( \
            a[mh][mf][ks], b[j][ks], acc[(mh)*4+mf][(nh)*2+j], 0, 0, 0); \
} while (0)

#define BAR8() __builtin_amdgcn_s_barrier()
#define VMC(n) asm volatile("s_waitcnt vmcnt(" #n ")" ::: "memory")

    // ---- prologue: tile0 (4 half-tiles) + tile1 {Blo, Alo, Ahi}
    STAGE8(0, 0, 0); STAGE8(0, 0, 1); STAGE8(1, 0, 0); STAGE8(1, 0, 1);
    VMC(4);
    STAGE8(1, 1, 0); STAGE8(0, 1, 0); STAGE8(0, 1, 1);
    VMC(6);                               // 14 issued, retire oldest 8 = all tile0
    BAR8();

#pragma unroll
    for (int t = 0; t < NT; ++t) {
        // P1: quadrant (0,0)
        LDA8(t, 0); LDB8(t, 0);
        if (t + 1 < NT) STAGE8(1, t + 1, 1);          // Bhi(t+1) -> other buf (always safe)
        BAR8(); __builtin_amdgcn_s_setprio(1); MFMAQ(0, 0); __builtin_amdgcn_s_setprio(0); BAR8();
        // P2: quadrant (1,0) — no staging (no region is sealed yet)
        LDA8(t, 1);
        BAR8(); __builtin_amdgcn_s_setprio(1); MFMAQ(1, 0); __builtin_amdgcn_s_setprio(0); BAR8();
        // P3: quadrant (0,1); A reads sealed by P2-end barrier
        LDB8(t, 1);
        if (t + 2 < NT) STAGE8(0, t + 2, 0);          // Alo(t+2)
        BAR8(); __builtin_amdgcn_s_setprio(1); MFMAQ(0, 1); __builtin_amdgcn_s_setprio(0); BAR8();
        // P4: quadrant (1,1); B reads sealed by P3-end barrier
        if (t + 2 < NT) { STAGE8(0, t + 2, 1);        // Ahi(t+2)
                          STAGE8(1, t + 2, 0); }      // Blo(t+2)
        BAR8(); __builtin_amdgcn_s_setprio(1); MFMAQ(1, 1); __builtin_amdgcn_s_setprio(0);
        if (t + 2 < NT)      { VMC(6); }              // retire Bhi(t+1): tile t+1 landed
        else if (t + 1 < NT) { VMC(0); }              // drain before last tile
        if (t + 1 < NT) BAR8();
    }

    // ---- epilogue: D row=(lane>>4)*4+reg, col=lane&15 (m89-verified)
    const int rb = row0 + wm * 128 + lg * 4;
    const int cb = col0 + wn * 64 + l15;
#pragma unroll
    for (int mf = 0; mf < 8; ++mf) {
#pragma unroll
        for (int nf = 0; nf < 4; ++nf) {
            const int c = cb + nf * 16;
            const float bv = bias[c];
            const long base = (long)(rb + mf * 16) * N + c;
#pragma unroll
            for (int r = 0; r < 4; ++r) {
                const float v = acc[mf][nf][r] + bv;
                if (OUT_BF16) ((ushort*)Cout)[base + (long)r * N] = f2b(v);
                else          ((float*)Cout)[base + (long)r * N]  = v;
            }
        }
    }
#undef STAGE8
#undef LDA8
#undef LDB8
#undef MFMAQ
#undef BAR8
#undef VMC
}

// ---------------------------------------------------------------------------
// K3 GEMM (r16 retile: 64x128 tile, BK=32, 4 waves, m97 2-barrier structure).
// 576 blocks (2.25 rounds) kills the r15 288-block 2-round tail. Same staging
// pattern (A: 1 GLL/thread, B: 2), same fragment addressing / m89 epilogue.
// Wave w owns output cols 32w..32w+31 (2 n-frags), all 64 rows (4 m-frags).
// ---------------------------------------------------------------------------
template<bool OUT_BF16>
__global__ __launch_bounds__(256) void mfma_gemm_nt_64(
    const ushort* __restrict__ A, const ushort* __restrict__ B,
    const float* __restrict__ bias, void* __restrict__ Cout,
    int M, int N, int K, long sA, long sB, long sC)
{
    // T1 XCD swizzle over the flattened 3D grid (576 % 8 == 0)
    const int gx = gridDim.x, gxy = gridDim.x * gridDim.y;
    const int flat = blockIdx.x + gx * blockIdx.y + gxy * blockIdx.z;
    const int cpx  = (gxy * gridDim.z) >> 3;
    const int swz  = (flat & 7) * cpx + (flat >> 3);
    const int bz = swz / gxy, rem = swz % gxy;
    const int row0 = (rem / gx) * 64, col0 = (rem % gx) * 128;

    A += (long)bz * sA;
    B += (long)bz * sB;

    __shared__ __align__(16) ushort As[64 * 32];    // 4 KB
    __shared__ __align__(16) ushort Bs[128 * 32];   // 8 KB

    const int tid  = threadIdx.x;
    const int lane = tid & 63;
    const int wave = tid >> 6;
    const int wc   = wave * 32;          // wave's output-col base within tile

    const int sr = tid >> 2;             // 0..63
    const int sc = (tid & 3) * 8;
    const ushort* gA0 = A + (long)(row0 + sr) * K + sc;
    const ushort* gB0 = B + (long)(col0 + sr) * K + sc;
    const ushort* gB1 = B + (long)(col0 + sr + 64) * K + sc;

    char* lA = (char*)As + wave * 1024;  // lane*16 appended by HW -> byte tid*16
    char* lB = (char*)Bs + wave * 1024;

    const int fr = lane & 15;
    const int kg = (lane >> 4) * 8;

    f32x4 acc[4][2] = {};

    for (int k0 = 0; k0 < K; k0 += 32) {
        if (k0) __syncthreads();
        GLL(gA0 + k0, lA);
        GLL(gB0 + k0, lB);
        GLL(gB1 + k0, lB + 4096);
        __syncthreads();

        short8 a[4], b[2];
        #pragma unroll
        for (int m = 0; m < 4; ++m)
            a[m] = *(const short8*)(As + (m * 16 + fr) * 32 + kg);
        #pragma unroll
        for (int n = 0; n < 2; ++n)
            b[n] = *(const short8*)(Bs + (wc + n * 16 + fr) * 32 + kg);

        #pragma unroll
        for (int m = 0; m < 4; ++m)
            #pragma unroll
            for (int n = 0; n < 2; ++n)
                acc[m][n] = __builtin_amdgcn_mfma_f32_16x16x32_bf16(
                    a[m], b[n], acc[m][n], 0, 0, 0);
    }

    const int rbase = row0 + (lane >> 4) * 4;
    const int cbase = col0 + wc + (lane & 15);
    const long zoff = (long)bz * sC;
    #pragma unroll
    for (int m = 0; m < 4; ++m) {
        #pragma unroll
        for (int n = 0; n < 2; ++n) {
            const int c = cbase + n * 16;
            const float bv = bias[c];
            #pragma unroll
            for (int r = 0; r < 4; ++r) {
                const long off = zoff + (long)(rbase + m * 16 + r) * N + c;
                const float v = acc[m][n][r] + bv;
                if (OUT_BF16) ((ushort*)Cout)[off] = f2b(v);
                else          ((float*)Cout)[off]  = v;
            }
        }
    }
}

// ---------------------------------------------------------------------------
// K2a (r15-verified MFMA): Mtp[chunk][bh][e][q] = bf16((1/8) Σ V[n][e] K[n][q])
// K,V staged TRANSPOSED [d][tok] with XOR swizzle; identical A/B addressing.
// ---------------------------------------------------------------------------
__global__ __launch_bounds__(256) void ktv_mfma(
    const ushort* __restrict__ y, ushort* __restrict__ Mtp)
{
    const int chunk = blockIdx.x;          // 0..5 (384 tokens each)
    const int bh    = blockIdx.y;          // 0..31
    const int b = bh >> 3, h = bh & 7;
    const ushort* Kp = y + (long)b * YB_STRIDE + QKV_SZ     + h * HDIM;
    const ushort* Vp = y + (long)b * YB_STRIDE + 2 * QKV_SZ + h * HDIM;

    __shared__ __align__(16) ushort Kt[64 * 64];   // [d][tok], swizzled, 8 KB
    __shared__ __align__(16) ushort Vt[64 * 64];

    const int tid  = threadIdx.x;
    const int lane = tid & 63, w = tid >> 6;       // wave w owns e-block 16w
    const int tloc = tid >> 2;                     // staged token 0..63
    const int d0   = (tid & 3) * 16;               // staged d range

    const int fr = lane & 15;                      // fragment row (q or e)
    const int kg = (lane >> 4) * 8;                // token chunk within k-step
    const int swr = (fr & 7) << 3;                 // read-side XOR (ushort units)

    f32x4 acc[4] = {};                             // m=0..3 -> q-blocks 16m

    for (int s = 0; s < 6; ++s) {
        const int n0 = chunk * 384 + s * 64;
        const ushort* kr = Kp + (long)(n0 + tloc) * CH + d0;
        const ushort* vr = Vp + (long)(n0 + tloc) * CH + d0;
        const uint4 k0 = *(const uint4*)kr;
        const uint4 k1 = *(const uint4*)(kr + 8);
        const uint4 v0 = *(const uint4*)vr;
        const uint4 v1 = *(const uint4*)(vr + 8);
        if (s) __syncthreads();
        const unsigned int kw[8] = {k0.x,k0.y,k0.z,k0.w,k1.x,k1.y,k1.z,k1.w};
        const unsigned int vw[8] = {v0.x,v0.y,v0.z,v0.w,v1.x,v1.y,v1.z,v1.w};
        #pragma unroll
        for (int j = 0; j < 16; ++j) {             // transpose-scatter to [d][tok]
            const int d   = d0 + j;
            const int idx = d * 64 + (tloc ^ ((d & 7) << 3));
            Kt[idx] = (ushort)(kw[j >> 1] >> ((j & 1) * 16));
            Vt[idx] = (ushort)(vw[j >> 1] >> ((j & 1) * 16));
        }
        __syncthreads();

        short8 a[4][2], bfrag[2];
        #pragma unroll
        for (int ks = 0; ks < 2; ++ks) {
            const int kc = (kg + 32 * ks) ^ swr;
            bfrag[ks] = *(const short8*)(Vt + (16 * w + fr) * 64 + kc);
            #pragma unroll
            for (int m = 0; m < 4; ++m)
                a[m][ks] = *(const short8*)(Kt + (16 * m + fr) * 64 + kc);
        }
        #pragma unroll
        for (int ks = 0; ks < 2; ++ks)
            #pragma unroll
            for (int m = 0; m < 4; ++m)
                acc[m] = __builtin_amdgcn_mfma_f32_16x16x32_bf16(
                    a[m][ks], bfrag[ks], acc[m], 0, 0, 0);
    }

    ushort* Mo = Mtp + ((long)chunk * 32 + bh) * 4096;
    const int e  = 16 * w + fr;
    const int lg = lane >> 4;
    #pragma unroll
    for (int m = 0; m < 4; ++m) {
        ushort4 st;
        st.x = f2b(acc[m][0] * 0.125f); st.y = f2b(acc[m][1] * 0.125f);
        st.z = f2b(acc[m][2] * 0.125f); st.w = f2b(acc[m][3] * 0.125f);
        *(ushort4*)&Mo[e * 64 + 16 * m + lg * 4] = st;
    }
}

// ---------------------------------------------------------------------------
// K2b (r14-verified vectorized): Pt[b][f][64h+q] = sum_e w_out[f][64h+e]*Ms[e][q]
// ---------------------------------------------------------------------------
__global__ __launch_bounds__(256) void fold_pt(
    const ushort* __restrict__ Mtp, const float* __restrict__ w_out,
    ushort* __restrict__ Pt)
{
    const int fc = blockIdx.x;   // 0..7
    const int bh = blockIdx.y;   // 0..31
    const int b = bh >> 3, h = bh & 7;

    __shared__ __align__(16) float Ms[64][68];   // [e(V-dim)][q(K-dim)]
    __shared__ __align__(16) float Ws[64][68];   // [f-local][e(V-dim)]

    const int tid = threadIdx.x;
    const int tx = tid & 15, ty = tid >> 4;
    const int r  = tid >> 2, c0 = (tid & 3) * 16;

    {
        const float* wr_ = w_out + (long)(fc * 64 + r) * CH + h * HDIM + c0;
        #pragma unroll
        for (int k = 0; k < 4; ++k)
            *(float4*)&Ws[r][c0 + 4 * k] = *(const float4*)(wr_ + 4 * k);
    }

    {
        const int e0 = tid * 16;
        float s[16] = {};
        #pragma unroll
        for (int c = 0; c < KVCHUNK; ++c) {
            const ushort* p = Mtp + ((long)c * 32 + bh) * 4096 + e0;
            const uint4 u0 = *(const uint4*)p;
            const uint4 u1 = *(const uint4*)(p + 8);
            const unsigned int uu[8] = {u0.x,u0.y,u0.z,u0.w,u1.x,u1.y,u1.z,u1.w};
            #pragma unroll
            for (int k = 0; k < 8; ++k) {
                float lo, hi; unp(uu[k], lo, hi);
                s[2*k] += lo; s[2*k+1] += hi;
            }
        }
        #pragma unroll
        for (int k = 0; k < 4; ++k) {
            float4 v; v.x = s[4*k]; v.y = s[4*k+1]; v.z = s[4*k+2]; v.w = s[4*k+3];
            *(float4*)&Ms[r][c0 + 4 * k] = v;
        }
    }
    __syncthreads();

    float acc[4][4] = {};
    for (int d = 0; d < 64; ++d) {
        const float4 mv = *(const float4*)&Ms[d][tx * 4];
        const float mm[4] = {mv.x, mv.y, mv.z, mv.w};
        #pragma unroll
        for (int i = 0; i < 4; ++i) {
            const float w = Ws[ty * 4 + i][d];
            #pragma unroll
            for (int j = 0; j < 4; ++j)
                acc[i][j] = fmaf(w, mm[j], acc[i][j]);
        }
    }
    const int fbase = fc * 64 + ty * 4;
    #pragma unroll
    for (int i = 0; i < 4; ++i) {
        ushort4 o;
        o.x = f2b(acc[i][0]); o.y = f2b(acc[i][1]);
        o.z = f2b(acc[i][2]); o.w = f2b(acc[i][3]);
        *(ushort4*)&Pt[(((long)b * CH) + fbase + i) * CH + h * HDIM + tx * 4] = o;
    }
}

// ---------------------------------------------------------------------------
extern "C" void kernel_launch(void* const* d_in, const int* in_sizes, int n_in,
                              void* d_out, int out_size, void* d_ws, size_t ws_size,
                              hipStream_t stream)
{
    const float* x     = (const float*)d_in[0];   // [4,2304,512]
    const float* w_in  = (const float*)d_in[1];   // [1536,512]
    const float* b_in  = (const float*)d_in[2];   // [1536]
    const float* w_out = (const float*)d_in[3];   // [512,512]
    const float* b_out = (const float*)d_in[4];   // [512]
    float* out = (float*)d_out;                   // [4,2304,512] fp32

    char* ws = (char*)d_ws;
    ushort* xb   = (ushort*)ws;                      //  9,437,184 B
    ushort* wb   = (ushort*)(ws + 9437184);          //  1,572,864 B (contig after xb)
    ushort* y    = (ushort*)(ws + 11010048);         // 28,311,552 B bf16 [4][2304][1536]
    ushort* Mtp  = (ushort*)(ws + 39321600);         //  1,572,864 B (6 chunks, bf16)
    ushort* Pt   = (ushort*)(ws + 40894464);         //  2,097,152 B -> 43.0 MB total

    // K0: converts (one launch; wb contiguous after xb)
    cvt_bf16_2<<<5376, 256, 0, stream>>>(x, w_in, xb, 1179648, 196608);

    // K1: y = x @ w_in^T + b_in  (bf16 out), 256^2 8-phase. M=9216 N=1536 K=512
    gemm256_8ph<512, true><<<dim3(F3 / 256, (BATCH * TOK) / 256), 512, 0, stream>>>(
        xb, wb, b_in, y, F3);

    // K2a: chunk-partial (V^T K)/8 via MFMA, 192 blocks (1 round)
    ktv_mfma<<<dim3(KVCHUNK, BATCH * NHEAD), 256, 0, stream>>>(y, Mtp);

    // K2b: vectorized reduce + fold w_out -> Pt bf16
    fold_pt<<<dim3(8, BATCH * NHEAD), 256, 0, stream>>>(Mtp, w_out, Pt);

    // K3: out[b] = Q[b] @ Pt[b]^T + b_out (fp32 out), 64x128 tiles, 576 blocks
    mfma_gemm_nt_64<false><<<dim3(CH / 128, TOK / 64, BATCH), 256, 0, stream>>>(
        y, Pt, b_out, out, TOK, CH, CH, YB_STRIDE, (long)CH * CH, QKV_SZ);
}

// Round 17
// 57.863 us; speedup vs baseline: 1.2359x; 1.0018x over previous
//
#include <hip/hip_runtime.h>
#include <hip/hip_bf16.h>

#define BATCH 4
#define TOK   2304
#define CH    512
#define NHEAD 8
#define HDIM  64
#define F3    1536
#define YB_STRIDE ((long)TOK * F3)   // y per-batch stride (elements)
#define QKV_SZ    ((long)TOK * CH)   // one Q/K/V third (elements)
#define KVCHUNK   6                  // token chunks for K^T V partials (2304/6=384)

typedef __attribute__((ext_vector_type(8))) short short8;   // 8 bf16 = 4 VGPRs
typedef __attribute__((ext_vector_type(4))) float f32x4;

__device__ inline ushort f2b(float f) {
    __hip_bfloat16 h = __float2bfloat16(f);
    return *reinterpret_cast<ushort*>(&h);
}
__device__ inline void unp(unsigned int u, float& lo, float& hi) {
    union { unsigned int i; float f; } a, c;
    a.i = u << 16; c.i = u & 0xffff0000u;
    lo = a.f; hi = c.f;
}

// global -> LDS direct copy, 16B per lane; lds dest = wave-uniform base + lane*16
#define GLL(gp, lp) __builtin_amdgcn_global_load_lds( \
    (const __attribute__((address_space(1))) unsigned int*)(gp), \
    (__attribute__((address_space(3))) unsigned int*)(lp), 16, 0, 0)

// ---------------------------------------------------------------------------
// K0 (r17 polish): fp32 -> bf16 convert, grid-stride 2048 blocks (G11),
// 32B/thread/iter (2 x float4 read, 1 x 16B store). x/w float4 boundary
// (1179648) is even so a pair never straddles regions.
// ---------------------------------------------------------------------------
__global__ __launch_bounds__(256) void cvt_bf16_2(
    const float* __restrict__ x, const float* __restrict__ w,
    ushort* __restrict__ xb_wb, int nx8, int ntot8)
{
    for (int i8 = blockIdx.x * 256 + threadIdx.x; i8 < ntot8;
         i8 += gridDim.x * 256) {
        const int i = i8 * 2;                         // float4 index (even)
        float4 v0, v1;
        if (i8 < nx8) { v0 = ((const float4*)x)[i];   v1 = ((const float4*)x)[i + 1]; }
        else { const int j = i - nx8 * 2;
               v0 = ((const float4*)w)[j];            v1 = ((const float4*)w)[j + 1]; }
        ushort o[8] = { f2b(v0.x), f2b(v0.y), f2b(v0.z), f2b(v0.w),
                        f2b(v1.x), f2b(v1.y), f2b(v1.z), f2b(v1.w) };
        *(uint4*)&xb_wb[i8 * 8] = *(const uint4*)o;
    }
}

// ---------------------------------------------------------------------------
// K1: 256x256-tile, BK=64, 8-wave (2Mx4N), 8-phase counted-vmcnt MFMA GEMM NT.
// (verified r5-r16) READ-SEAL: P1:Bhi(t+1)[other buf] P3:Alo(t+2) P4:Ahi,Blo(t+2)
// Ledger: end-of-t VMC(6) leaves {Alo,Ahi,Blo}(t+2) in flight; t=NT-2: VMC(0).
// ---------------------------------------------------------------------------
template<int KDIM, bool OUT_BF16>
__global__ __launch_bounds__(512, 2) void gemm256_8ph(
    const ushort* __restrict__ A, const ushort* __restrict__ B,
    const float* __restrict__ bias, void* __restrict__ Cout, int N)
{
    constexpr int NT = KDIM / 64;
    __shared__ __align__(16) char smem[131072];

    const int tid  = threadIdx.x;
    const int lane = tid & 63, wave = tid >> 6;
    const int wm = wave >> 2, wn = wave & 3;           // 2 x 4 wave grid

    // T1 XCD swizzle (nwg % 8 == 0 by construction: 216 blocks)
    const int nbx  = gridDim.x;
    const int flat = blockIdx.x + nbx * blockIdx.y;
    const int cpx  = (nbx * gridDim.y) >> 3;
    const int swz  = (flat & 7) * cpx + (flat >> 3);
    const int row0 = (swz / nbx) * 256, col0 = (swz % nbx) * 256;

    // staging invariants: thread covers LDS linear (srow, (tid&7)*16B) per chunk
    const int srow = tid >> 3;                          // 0..63 within chunk
    const int scol = ((tid & 7) ^ (srow & 7)) << 3;     // inverse-swizzled src col (elems)
    const ushort* gA = A + (long)(row0 + srow) * KDIM + scol;
    const ushort* gB = B + (long)(col0 + srow) * KDIM + scol;
    char* ldsW = smem + wave * 1024;                    // + op*65536 + buf*32768 + half*16384 + chunk*8192

    // fragment-read invariants
    const int l15 = lane & 15, lg = lane >> 4, l7 = lane & 7;
    const int cp[2] = { (lg * 16) ^ (l7 * 16), (64 + lg * 16) ^ (l7 * 16) };
    const char* rdA = smem + (wm * 128 + l15) * 128;
    const char* rdB = smem + 65536 + (wn * 64 + l15) * 128;

    f32x4  acc[8][4] = {};
    short8 a[2][4][2], b[2][2];

#define STAGE8(op, t, h) do { \
    const ushort* _g = ((op) ? gB : gA) + ((h) * 128) * KDIM + (t) * 64; \
    char* _l = ldsW + (op) * 65536 + ((t) & 1) * 32768 + (h) * 16384; \
    GLL(_g, _l); \
    GLL(_g + 64 * KDIM, _l + 8192); \
} while (0)

#define LDA8(t, mh) do { \
    const char* _p = rdA + ((t) & 1) * 32768 + (mh) * 8192; \
    _Pragma("unroll") for (int mf = 0; mf < 4; ++mf) { \
        a[mh][mf][0] = *(const short8*)(_p + mf * 2048 + cp[0]); \
        a[mh][mf][1] = *(const short8*)(_p + mf * 2048 + cp[1]); } \
} while (0)

#define LDB8(t, nh) do { \
    const char* _p = rdB + ((t) & 1) * 32768 + (nh) * 4096; \
    _Pragma("unroll") for (int j = 0; j < 2; ++j) { \
        b[j][0] = *(const short8*)(_p + j * 2048 + cp[0]); \
        b[j][1] = *(const short8*)(_p + j * 2048 + cp[1]); } \
} while (0)

#define MFMAQ(mh, nh) do { \
    _Pragma("unroll") for (int mf = 0; mf < 4; ++mf) \
    _Pragma("unroll") for (int j = 0; j < 2; ++j) \
    _Pragma("unroll") for (int ks = 0; ks < 2; ++ks) \
        acc[(mh)*4+mf][(nh)*2+j] = __builtin_amdgcn_mfma_f32_16x16x32_bf16( \
            a[mh][mf][ks], b[j][ks], acc[(mh)*4+mf][(nh)*2+j], 0, 0, 0); \
} while (0)

#define BAR8() __builtin_amdgcn_s_barrier()
#define VMC(n) asm volatile("s_waitcnt vmcnt(" #n ")" ::: "memory")

    // ---- prologue: tile0 (4 half-tiles) + tile1 {Blo, Alo, Ahi}
    STAGE8(0, 0, 0); STAGE8(0, 0, 1); STAGE8(1, 0, 0); STAGE8(1, 0, 1);
    VMC(4);
    STAGE8(1, 1, 0); STAGE8(0, 1, 0); STAGE8(0, 1, 1);
    VMC(6);                               // 14 issued, retire oldest 8 = all tile0
    BAR8();

#pragma unroll
    for (int t = 0; t < NT; ++t) {
        // P1: quadrant (0,0)
        LDA8(t, 0); LDB8(t, 0);
        if (t + 1 < NT) STAGE8(1, t + 1, 1);          // Bhi(t+1) -> other buf (always safe)
        BAR8(); __builtin_amdgcn_s_setprio(1); MFMAQ(0, 0); __builtin_amdgcn_s_setprio(0); BAR8();
        // P2: quadrant (1,0) — no staging (no region is sealed yet)
        LDA8(t, 1);
        BAR8(); __builtin_amdgcn_s_setprio(1); MFMAQ(1, 0); __builtin_amdgcn_s_setprio(0); BAR8();
        // P3: quadrant (0,1); A reads sealed by P2-end barrier
        LDB8(t, 1);
        if (t + 2 < NT) STAGE8(0, t + 2, 0);          // Alo(t+2)
        BAR8(); __builtin_amdgcn_s_setprio(1); MFMAQ(0, 1); __builtin_amdgcn_s_setprio(0); BAR8();
        // P4: quadrant (1,1); B reads sealed by P3-end barrier
        if (t + 2 < NT) { STAGE8(0, t + 2, 1);        // Ahi(t+2)
                          STAGE8(1, t + 2, 0); }      // Blo(t+2)
        BAR8(); __builtin_amdgcn_s_setprio(1); MFMAQ(1, 1); __builtin_amdgcn_s_setprio(0);
        if (t + 2 < NT)      { VMC(6); }              // retire Bhi(t+1): tile t+1 landed
        else if (t + 1 < NT) { VMC(0); }              // drain before last tile
        if (t + 1 < NT) BAR8();
    }

    // ---- epilogue: D row=(lane>>4)*4+reg, col=lane&15 (m89-verified)
    const int rb = row0 + wm * 128 + lg * 4;
    const int cb = col0 + wn * 64 + l15;
#pragma unroll
    for (int mf = 0; mf < 8; ++mf) {
#pragma unroll
        for (int nf = 0; nf < 4; ++nf) {
            const int c = cb + nf * 16;
            const float bv = bias[c];
            const long base = (long)(rb + mf * 16) * N + c;
#pragma unroll
            for (int r = 0; r < 4; ++r) {
                const float v = acc[mf][nf][r] + bv;
                if (OUT_BF16) ((ushort*)Cout)[base + (long)r * N] = f2b(v);
                else          ((float*)Cout)[base + (long)r * N]  = v;
            }
        }
    }
#undef STAGE8
#undef LDA8
#undef LDB8
#undef MFMAQ
#undef BAR8
#undef VMC
}

// ---------------------------------------------------------------------------
// K3 GEMM (r16-verified: 64x128 tile, BK=32, 4 waves, m97 2-barrier structure).
// ---------------------------------------------------------------------------
template<bool OUT_BF16>
__global__ __launch_bounds__(256) void mfma_gemm_nt_64(
    const ushort* __restrict__ A, const ushort* __restrict__ B,
    const float* __restrict__ bias, void* __restrict__ Cout,
    int M, int N, int K, long sA, long sB, long sC)
{
    // T1 XCD swizzle over the flattened 3D grid (576 % 8 == 0)
    const int gx = gridDim.x, gxy = gridDim.x * gridDim.y;
    const int flat = blockIdx.x + gx * blockIdx.y + gxy * blockIdx.z;
    const int cpx  = (gxy * gridDim.z) >> 3;
    const int swz  = (flat & 7) * cpx + (flat >> 3);
    const int bz = swz / gxy, rem = swz % gxy;
    const int row0 = (rem / gx) * 64, col0 = (rem % gx) * 128;

    A += (long)bz * sA;
    B += (long)bz * sB;

    __shared__ __align__(16) ushort As[64 * 32];    // 4 KB
    __shared__ __align__(16) ushort Bs[128 * 32];   // 8 KB

    const int tid  = threadIdx.x;
    const int lane = tid & 63;
    const int wave = tid >> 6;
    const int wc   = wave * 32;          // wave's output-col base within tile

    const int sr = tid >> 2;             // 0..63
    const int sc = (tid & 3) * 8;
    const ushort* gA0 = A + (long)(row0 + sr) * K + sc;
    const ushort* gB0 = B + (long)(col0 + sr) * K + sc;
    const ushort* gB1 = B + (long)(col0 + sr + 64) * K + sc;

    char* lA = (char*)As + wave * 1024;
    char* lB = (char*)Bs + wave * 1024;

    const int fr = lane & 15;
    const int kg = (lane >> 4) * 8;

    f32x4 acc[4][2] = {};

    for (int k0 = 0; k0 < K; k0 += 32) {
        if (k0) __syncthreads();
        GLL(gA0 + k0, lA);
        GLL(gB0 + k0, lB);
        GLL(gB1 + k0, lB + 4096);
        __syncthreads();

        short8 a[4], b[2];
        #pragma unroll
        for (int m = 0; m < 4; ++m)
            a[m] = *(const short8*)(As + (m * 16 + fr) * 32 + kg);
        #pragma unroll
        for (int n = 0; n < 2; ++n)
            b[n] = *(const short8*)(Bs + (wc + n * 16 + fr) * 32 + kg);

        #pragma unroll
        for (int m = 0; m < 4; ++m)
            #pragma unroll
            for (int n = 0; n < 2; ++n)
                acc[m][n] = __builtin_amdgcn_mfma_f32_16x16x32_bf16(
                    a[m], b[n], acc[m][n], 0, 0, 0);
    }

    const int rbase = row0 + (lane >> 4) * 4;
    const int cbase = col0 + wc + (lane & 15);
    const long zoff = (long)bz * sC;
    #pragma unroll
    for (int m = 0; m < 4; ++m) {
        #pragma unroll
        for (int n = 0; n < 2; ++n) {
            const int c = cbase + n * 16;
            const float bv = bias[c];
            #pragma unroll
            for (int r = 0; r < 4; ++r) {
                const long off = zoff + (long)(rbase + m * 16 + r) * N + c;
                const float v = acc[m][n][r] + bv;
                if (OUT_BF16) ((ushort*)Cout)[off] = f2b(v);
                else          ((float*)Cout)[off]  = v;
            }
        }
    }
}

// ---------------------------------------------------------------------------
// K2a (r15-verified MFMA): Mtp[chunk][bh][e][q] = bf16((1/8) Σ V[n][e] K[n][q])
// K,V staged TRANSPOSED [d][tok] with XOR swizzle; identical A/B addressing.
// ---------------------------------------------------------------------------
__global__ __launch_bounds__(256) void ktv_mfma(
    const ushort* __restrict__ y, ushort* __restrict__ Mtp)
{
    const int chunk = blockIdx.x;          // 0..5 (384 tokens each)
    const int bh    = blockIdx.y;          // 0..31
    const int b = bh >> 3, h = bh & 7;
    const ushort* Kp = y + (long)b * YB_STRIDE + QKV_SZ     + h * HDIM;
    const ushort* Vp = y + (long)b * YB_STRIDE + 2 * QKV_SZ + h * HDIM;

    __shared__ __align__(16) ushort Kt[64 * 64];   // [d][tok], swizzled, 8 KB
    __shared__ __align__(16) ushort Vt[64 * 64];

    const int tid  = threadIdx.x;
    const int lane = tid & 63, w = tid >> 6;       // wave w owns e-block 16w
    const int tloc = tid >> 2;                     // staged token 0..63
    const int d0   = (tid & 3) * 16;               // staged d range

    const int fr = lane & 15;                      // fragment row (q or e)
    const int kg = (lane >> 4) * 8;                // token chunk within k-step
    const int swr = (fr & 7) << 3;                 // read-side XOR (ushort units)

    f32x4 acc[4] = {};                             // m=0..3 -> q-blocks 16m

    for (int s = 0; s < 6; ++s) {
        const int n0 = chunk * 384 + s * 64;
        const ushort* kr = Kp + (long)(n0 + tloc) * CH + d0;
        const ushort* vr = Vp + (long)(n0 + tloc) * CH + d0;
        const uint4 k0 = *(const uint4*)kr;
        const uint4 k1 = *(const uint4*)(kr + 8);
        const uint4 v0 = *(const uint4*)vr;
        const uint4 v1 = *(const uint4*)(vr + 8);
        if (s) __syncthreads();
        const unsigned int kw[8] = {k0.x,k0.y,k0.z,k0.w,k1.x,k1.y,k1.z,k1.w};
        const unsigned int vw[8] = {v0.x,v0.y,v0.z,v0.w,v1.x,v1.y,v1.z,v1.w};
        #pragma unroll
        for (int j = 0; j < 16; ++j) {             // transpose-scatter to [d][tok]
            const int d   = d0 + j;
            const int idx = d * 64 + (tloc ^ ((d & 7) << 3));
            Kt[idx] = (ushort)(kw[j >> 1] >> ((j & 1) * 16));
            Vt[idx] = (ushort)(vw[j >> 1] >> ((j & 1) * 16));
        }
        __syncthreads();

        short8 a[4][2], bfrag[2];
        #pragma unroll
        for (int ks = 0; ks < 2; ++ks) {
            const int kc = (kg + 32 * ks) ^ swr;
            bfrag[ks] = *(const short8*)(Vt + (16 * w + fr) * 64 + kc);
            #pragma unroll
            for (int m = 0; m < 4; ++m)
                a[m][ks] = *(const short8*)(Kt + (16 * m + fr) * 64 + kc);
        }
        #pragma unroll
        for (int ks = 0; ks < 2; ++ks)
            #pragma unroll
            for (int m = 0; m < 4; ++m)
                acc[m] = __builtin_amdgcn_mfma_f32_16x16x32_bf16(
                    a[m][ks], bfrag[ks], acc[m], 0, 0, 0);
    }

    ushort* Mo = Mtp + ((long)chunk * 32 + bh) * 4096;
    const int e  = 16 * w + fr;
    const int lg = lane >> 4;
    #pragma unroll
    for (int m = 0; m < 4; ++m) {
        ushort4 st;
        st.x = f2b(acc[m][0] * 0.125f); st.y = f2b(acc[m][1] * 0.125f);
        st.z = f2b(acc[m][2] * 0.125f); st.w = f2b(acc[m][3] * 0.125f);
        *(ushort4*)&Mo[e * 64 + 16 * m + lg * 4] = st;
    }
}

// ---------------------------------------------------------------------------
// K2b (r14-verified vectorized): Pt[b][f][64h+q] = sum_e w_out[f][64h+e]*Ms[e][q]
// ---------------------------------------------------------------------------
__global__ __launch_bounds__(256) void fold_pt(
    const ushort* __restrict__ Mtp, const float* __restrict__ w_out,
    ushort* __restrict__ Pt)
{
    const int fc = blockIdx.x;   // 0..7
    const int bh = blockIdx.y;   // 0..31
    const int b = bh >> 3, h = bh & 7;

    __shared__ __align__(16) float Ms[64][68];   // [e(V-dim)][q(K-dim)]
    __shared__ __align__(16) float Ws[64][68];   // [f-local][e(V-dim)]

    const int tid = threadIdx.x;
    const int tx = tid & 15, ty = tid >> 4;
    const int r  = tid >> 2, c0 = (tid & 3) * 16;

    {
        const float* wr_ = w_out + (long)(fc * 64 + r) * CH + h * HDIM + c0;
        #pragma unroll
        for (int k = 0; k < 4; ++k)
            *(float4*)&Ws[r][c0 + 4 * k] = *(const float4*)(wr_ + 4 * k);
    }

    {
        const int e0 = tid * 16;
        float s[16] = {};
        #pragma unroll
        for (int c = 0; c < KVCHUNK; ++c) {
            const ushort* p = Mtp + ((long)c * 32 + bh) * 4096 + e0;
            const uint4 u0 = *(const uint4*)p;
            const uint4 u1 = *(const uint4*)(p + 8);
            const unsigned int uu[8] = {u0.x,u0.y,u0.z,u0.w,u1.x,u1.y,u1.z,u1.w};
            #pragma unroll
            for (int k = 0; k < 8; ++k) {
                float lo, hi; unp(uu[k], lo, hi);
                s[2*k] += lo; s[2*k+1] += hi;
            }
        }
        #pragma unroll
        for (int k = 0; k < 4; ++k) {
            float4 v; v.x = s[4*k]; v.y = s[4*k+1]; v.z = s[4*k+2]; v.w = s[4*k+3];
            *(float4*)&Ms[r][c0 + 4 * k] = v;
        }
    }
    __syncthreads();

    float acc[4][4] = {};
    for (int d = 0; d < 64; ++d) {
        const float4 mv = *(const float4*)&Ms[d][tx * 4];
        const float mm[4] = {mv.x, mv.y, mv.z, mv.w};
        #pragma unroll
        for (int i = 0; i < 4; ++i) {
            const float w = Ws[ty * 4 + i][d];
            #pragma unroll
            for (int j = 0; j < 4; ++j)
                acc[i][j] = fmaf(w, mm[j], acc[i][j]);
        }
    }
    const int fbase = fc * 64 + ty * 4;
    #pragma unroll
    for (int i = 0; i < 4; ++i) {
        ushort4 o;
        o.x = f2b(acc[i][0]); o.y = f2b(acc[i][1]);
        o.z = f2b(acc[i][2]); o.w = f2b(acc[i][3]);
        *(ushort4*)&Pt[(((long)b * CH) + fbase + i) * CH + h * HDIM + tx * 4] = o;
    }
}

// ---------------------------------------------------------------------------
extern "C" void kernel_launch(void* const* d_in, const int* in_sizes, int n_in,
                              void* d_out, int out_size, void* d_ws, size_t ws_size,
                              hipStream_t stream)
{
    const float* x     = (const float*)d_in[0];   // [4,2304,512]
    const float* w_in  = (const float*)d_in[1];   // [1536,512]
    const float* b_in  = (const float*)d_in[2];   // [1536]
    const float* w_out = (const float*)d_in[3];   // [512,512]
    const float* b_out = (const float*)d_in[4];   // [512]
    float* out = (float*)d_out;                   // [4,2304,512] fp32

    char* ws = (char*)d_ws;
    ushort* xb   = (ushort*)ws;                      //  9,437,184 B
    ushort* wb   = (ushort*)(ws + 9437184);          //  1,572,864 B (contig after xb)
    ushort* y    = (ushort*)(ws + 11010048);         // 28,311,552 B bf16 [4][2304][1536]
    ushort* Mtp  = (ushort*)(ws + 39321600);         //  1,572,864 B (6 chunks, bf16)
    ushort* Pt   = (ushort*)(ws + 40894464);         //  2,097,152 B -> 43.0 MB total

    // K0: converts (grid-stride, 2048 blocks; nx8 = 589824 pairs, ntot8 = 688128)
    cvt_bf16_2<<<2048, 256, 0, stream>>>(x, w_in, xb, 589824, 688128);

    // K1: y = x @ w_in^T + b_in  (bf16 out), 256^2 8-phase. M=9216 N=1536 K=512
    gemm256_8ph<512, true><<<dim3(F3 / 256, (BATCH * TOK) / 256), 512, 0, stream>>>(
        xb, wb, b_in, y, F3);

    // K2a: chunk-partial (V^T K)/8 via MFMA, 192 blocks (1 round)
    ktv_mfma<<<dim3(KVCHUNK, BATCH * NHEAD), 256, 0, stream>>>(y, Mtp);

    // K2b: vectorized reduce + fold w_out -> Pt bf16
    fold_pt<<<dim3(8, BATCH * NHEAD), 256, 0, stream>>>(Mtp, w_out, Pt);

    // K3: out[b] = Q[b] @ Pt[b]^T + b_out (fp32 out), 64x128 tiles, 576 blocks
    mfma_gemm_nt_64<false><<<dim3(CH / 128, TOK / 64, BATCH), 256, 0, stream>>>(
        y, Pt, b_out, out, TOK, CH, CH, YB_STRIDE, (long)CH * CH, QKV_SZ);
}